// Round 2
// baseline (156.038 us; speedup 1.0000x reference)
//
#include <hip/hip_runtime.h>
#include <math.h>

#ifndef M_PI
#define M_PI 3.14159265358979323846
#endif

// JPEG base quantization tables (values are exact integers)
static __device__ const double LUM_BASE[64] = {
 16,11,10,16,24,40,51,61,
 12,12,14,19,26,58,60,55,
 14,13,16,24,40,57,69,56,
 14,17,22,29,51,87,80,62,
 18,22,37,56,68,109,103,77,
 24,35,55,64,81,104,113,92,
 49,64,78,87,103,121,120,101,
 72,92,95,98,112,100,103,99};
static __device__ const double CHROM_BASE[64] = {
 17,18,24,47,99,99,99,99,
 18,21,26,66,99,99,99,99,
 24,26,56,99,99,99,99,99,
 47,66,99,99,99,99,99,99,
 99,99,99,99,99,99,99,99,
 99,99,99,99,99,99,99,99,
 99,99,99,99,99,99,99,99,
 99,99,99,99,99,99,99,99};

// One workgroup = one strip of 8 rows x 64 cols of one image (8 8x8 blocks),
// all 3 channels. 16 images x 64 row-strips x 8 col-strips = 8192 workgroups.
__global__ __launch_bounds__(256) void jpeg_fwd(const float* __restrict__ img,
                                                const int* __restrict__ quality,
                                                float* __restrict__ out)
{
    __shared__ double A[3][8][64];   // ping
    __shared__ double B[3][8][64];   // pong
    __shared__ double Md[64];        // DCT matrix, full f64
    __shared__ double QT[128];       // [2][8][8] scaled quant tables, full f64

    const int t = threadIdx.x;

    // DCT matrix in full double precision (no f32 round-trip)
    if (t < 64) {
        int k = t >> 3, n = t & 7;
        double norm = (k == 0) ? sqrt(1.0 / 8.0) : sqrt(2.0 / 8.0);
        Md[t] = norm * cos(M_PI / 8.0 * ((double)n + 0.5) * (double)k);
    }
    // Quant tables in full double precision
    if (t >= 64 && t < 192) {
        int qi  = t - 64;
        int tbl = qi >> 6, e = qi & 63;
        int q   = quality[0];
        q = q < 1 ? 1 : (q > 100 ? 100 : q);
        double scale = (q < 50) ? (5000.0 / (double)q) : (200.0 - 2.0 * (double)q);
        double base  = tbl ? CHROM_BASE[e] : LUM_BASE[e];
        double v = (base * scale + 50.0) / 100.0;
        v = fmin(fmax(v, 1.0), 255.0);
        QT[qi] = v;
    }

    // Strip coordinates
    const int sid  = blockIdx.x;
    const int b    = sid >> 9;          // image index (512 strips per image)
    const int rem  = sid & 511;
    const int row0 = (rem >> 3) << 3;   // strip row * 8
    const int col0 = (rem & 7) << 6;    // strip col * 64

    // Exact f64 YCbCr weights
    const double W00 =  0.299,   W01 =  0.587,   W02 =  0.114;
    const double W10 = -0.1687,  W11 = -0.3313,  W12 =  0.5;
    const double W20 =  0.5,     W21 = -0.4187,  W22 = -0.0813;

    // Phase 1: load RGB, x*255, -> YCbCr (+b_ycc), subtract 128, stage to LDS
    for (int p = t; p < 512; p += 256) {
        int pr = p >> 6, pc = p & 63;
        int gbase = ((b * 3) * 512 + row0 + pr) * 512 + col0 + pc;
        double r  = (double)img[gbase]                 * 255.0;
        double g  = (double)img[gbase + 512 * 512]     * 255.0;
        double bl = (double)img[gbase + 2 * 512 * 512] * 255.0;
        double y  = W00 * r + W01 * g + W02 * bl;          // b_ycc[0] = 0
        double cb = W10 * r + W11 * g + W12 * bl + 128.0;
        double cr = W20 * r + W21 * g + W22 * bl + 128.0;
        A[0][pr][pc] = y  - 128.0;
        A[1][pr][pc] = cb - 128.0;
        A[2][pr][pc] = cr - 128.0;
    }
    __syncthreads();

    // Phase 2: row transform (X-128) @ M^T : out[r][bk+c] = sum_k X[r][bk+k] * M[c][k]
    for (int i = 0; i < 6; ++i) {
        int idx = t + (i << 8);             // 0..1535
        int ch  = idx >> 9;
        int r   = (idx >> 6) & 7;
        int col = idx & 63;
        int bk  = col & ~7;
        int c   = col & 7;
        double s = 0.0;
        #pragma unroll
        for (int k = 0; k < 8; ++k)
            s += A[ch][r][bk + k] * Md[(c << 3) + k];
        B[ch][r][col] = s;
    }
    __syncthreads();

    // Phase 3: column transform M @ tmp, then quantize: tq = rint(dct/q)*q
    for (int i = 0; i < 6; ++i) {
        int idx = t + (i << 8);
        int ch  = idx >> 9;
        int r   = (idx >> 6) & 7;
        int col = idx & 63;
        double s = 0.0;
        #pragma unroll
        for (int k = 0; k < 8; ++k)
            s += Md[(r << 3) + k] * B[ch][k][col];
        // Reference quirk: table selected by flattened (b*3+ch) < bs, NOT by channel
        int sel = ((b * 3 + ch) < 16) ? 0 : 1;
        double q = QT[(sel << 6) + (r << 3) + (col & 7)];
        A[ch][r][col] = rint(s / q) * q;    // round half-to-even, like jnp.round
    }
    __syncthreads();

    // Phase 4: row transform tq @ M : out[r][bk+c] = sum_k tq[r][bk+k] * M[k][c]
    for (int i = 0; i < 6; ++i) {
        int idx = t + (i << 8);
        int ch  = idx >> 9;
        int r   = (idx >> 6) & 7;
        int col = idx & 63;
        int bk  = col & ~7;
        int c   = col & 7;
        double s = 0.0;
        #pragma unroll
        for (int k = 0; k < 8; ++k)
            s += A[ch][r][bk + k] * Md[(k << 3) + c];
        B[ch][r][col] = s;
    }
    __syncthreads();

    // Phase 5: column transform M^T @ tmp, +128
    for (int i = 0; i < 6; ++i) {
        int idx = t + (i << 8);
        int ch  = idx >> 9;
        int r   = (idx >> 6) & 7;
        int col = idx & 63;
        double s = 0.0;
        #pragma unroll
        for (int k = 0; k < 8; ++k)
            s += Md[(k << 3) + r] * B[ch][k][col];
        A[ch][r][col] = s + 128.0;
    }
    __syncthreads();

    // Phase 6: YCbCr -> RGB, /255, clip, store
    for (int p = t; p < 512; p += 256) {
        int pr = p >> 6, pc = p & 63;
        double y  = A[0][pr][pc];
        double cb = A[1][pr][pc] - 128.0;
        double cr = A[2][pr][pc] - 128.0;
        double r  = y + 1.402 * cr;
        double g  = y - 0.34414 * cb - 0.71414 * cr;
        double bl = y + 1.772 * cb;
        int gbase = ((b * 3) * 512 + row0 + pr) * 512 + col0 + pc;
        out[gbase]                 = (float)fmin(fmax(r  / 255.0, 0.0), 1.0);
        out[gbase + 512 * 512]     = (float)fmin(fmax(g  / 255.0, 0.0), 1.0);
        out[gbase + 2 * 512 * 512] = (float)fmin(fmax(bl / 255.0, 0.0), 1.0);
    }
}

extern "C" void kernel_launch(void* const* d_in, const int* in_sizes, int n_in,
                              void* d_out, int out_size, void* d_ws, size_t ws_size,
                              hipStream_t stream) {
    const float* img     = (const float*)d_in[0];
    const int*   quality = (const int*)d_in[1];
    float*       out     = (float*)d_out;
    // 16 images * 64 row-strips * 8 col-strips = 8192 workgroups
    jpeg_fwd<<<8192, 256, 0, stream>>>(img, quality, out);
}